// Round 8
// baseline (358.428 us; speedup 1.0000x reference)
//
#include <hip/hip_runtime.h>
#include <stdint.h>

#define NPTS 8192
#define DIM  512
#define ODIM 512

typedef __attribute__((ext_vector_type(8))) short short8;
typedef __attribute__((ext_vector_type(4))) float f32x4;

__device__ __forceinline__ void gload_lds16(const void* g, void* l) {
  __builtin_amdgcn_global_load_lds(
      (__attribute__((address_space(1))) void*)g,
      (__attribute__((address_space(3))) void*)l, 16, 0, 0);
}

// round-to-nearest-even f32 -> bf16 bits (values are finite here)
__device__ __forceinline__ short f2bf(float f) {
  uint32_t u = __float_as_uint(f);
  u = (u + 0x7FFFu + ((u >> 16) & 1u)) >> 16;
  return (short)u;
}

// ---------------------------------------------------------------------------
// 128x128 NT GEMM core, BK=64, 4 waves (2x2), SINGLE-buffer 32 KiB LDS.
// m97 mechanism: stage -> sync(drain) -> compute -> sync, relying on 4-5
// co-resident blocks/CU for latency overlap (m114 inter-block overlap),
// instead of intra-block pipelining (rounds 2-7: 1 block/CU, 15-19% MfmaUtil).
// T2 swizzle: LDS row r slot s holds logical chunk s^(r&7); applied via
// pre-swizzled global source (linear LDS dest) + same XOR on ds_read ->
// conflict-free ds_read_b128.
// Per K-tile per wave: 16 ds_read_b128 + 32 MFMA; 8 gloads/thread.
// ---------------------------------------------------------------------------
__device__ __forceinline__ void gemm128(const short* __restrict__ A,
                                        const short* __restrict__ B,
                                        int K, int lda, int ldb,
                                        short* lds, f32x4 acc[4][4]) {
  const int tid = threadIdx.x, wid = tid >> 6, lane = tid & 63;
  const int wr = wid >> 1, wc = wid & 1, fr = lane & 15, fg = (lane >> 4) & 3;
  const int nt = K >> 6;
  const short* srcA[4]; const short* srcB[4]; int dst[4];
#pragma unroll
  for (int u = 0; u < 4; ++u) {
    const int g = u * 256 + tid;            // global chunk id (16B units)
    const int r = g >> 3;                   // row 0..127
    const int cl = (g & 7) ^ (r & 7);       // pre-swizzled source chunk
    srcA[u] = A + (size_t)r * lda + cl * 8;
    srcB[u] = B + (size_t)r * ldb + cl * 8;
    dst[u] = (u * 256 + wid * 64) * 8;      // wave-uniform dest (shorts)
  }
  short* sB = lds + 8192;
  const int c0 = (fg ^ (fr & 7)) * 8;
  const int c1 = ((4 + fg) ^ (fr & 7)) * 8;

  for (int t = 0; t < nt; ++t) {
    const int k0 = t << 6;
#pragma unroll
    for (int u = 0; u < 4; ++u) gload_lds16(srcA[u] + k0, lds + dst[u]);
#pragma unroll
    for (int u = 0; u < 4; ++u) gload_lds16(srcB[u] + k0, sB + dst[u]);
    __syncthreads();                        // drains vmcnt: tile visible
    short8 af[4][2], bb[4][2];
#pragma unroll
    for (int m = 0; m < 4; ++m) {
      const int rr = (wr * 64 + m * 16 + fr) * 64;
      af[m][0] = *(const short8*)(lds + rr + c0);
      af[m][1] = *(const short8*)(lds + rr + c1);
    }
#pragma unroll
    for (int n = 0; n < 4; ++n) {
      const int rr = (wc * 64 + n * 16 + fr) * 64;
      bb[n][0] = *(const short8*)(sB + rr + c0);
      bb[n][1] = *(const short8*)(sB + rr + c1);
    }
#pragma unroll
    for (int kk = 0; kk < 2; ++kk)
#pragma unroll
      for (int m = 0; m < 4; ++m)
#pragma unroll
        for (int n = 0; n < 4; ++n)
          acc[m][n] = __builtin_amdgcn_mfma_f32_16x16x32_bf16(af[m][kk], bb[n][kk], acc[m][n], 0, 0, 0);
    __syncthreads();                        // reads done before next overwrite
  }
}

#define ZERO_ACC4(acc)                       \
  {                                          \
    f32x4 _z = {0.f, 0.f, 0.f, 0.f};         \
    _Pragma("unroll")                        \
    for (int m = 0; m < 4; ++m)              \
      _Pragma("unroll")                      \
      for (int n = 0; n < 4; ++n) acc[m][n] = _z; \
  }

// ---------------------------------------------------------------------------
// legacy 128x128 BK=32 core (small YbT GEMM only)
// ---------------------------------------------------------------------------
__device__ __forceinline__ void gemm_core_nt(const short* __restrict__ A,
                                             const short* __restrict__ B,
                                             int K, int lda, int ldb,
                                             short* smem, f32x4 acc[4][4]) {
  const int tid  = threadIdx.x;
  const int wid  = tid >> 6;
  const int lane = tid & 63;
  const int wr = wid >> 1, wc = wid & 1;
  const int sr = lane >> 2;
  const int sc = (lane & 3) << 3;
  const int fr = lane & 15, fg = lane >> 4;
  short* sA = smem;
  short* sB = smem + 4096;
  short* dA0 = sA + wid * 512;
  short* dA1 = sA + 2048 + wid * 512;
  short* dB0 = sB + wid * 512;
  short* dB1 = sB + 2048 + wid * 512;
  const short* pa0 = A + (size_t)(wid * 16 + sr) * lda + sc;
  const short* pa1 = A + (size_t)(64 + wid * 16 + sr) * lda + sc;
  const short* pb0 = B + (size_t)(wid * 16 + sr) * ldb + sc;
  const short* pb1 = B + (size_t)(64 + wid * 16 + sr) * ldb + sc;

  for (int k0 = 0; k0 < K; k0 += 32) {
    gload_lds16(pa0 + k0, dA0);
    gload_lds16(pa1 + k0, dA1);
    gload_lds16(pb0 + k0, dB0);
    gload_lds16(pb1 + k0, dB1);
    __syncthreads();
    short8 af[4], bb[4];
#pragma unroll
    for (int m = 0; m < 4; ++m)
      af[m] = *(const short8*)(sA + (wr * 64 + m * 16 + fr) * 32 + fg * 8);
#pragma unroll
    for (int n = 0; n < 4; ++n)
      bb[n] = *(const short8*)(sB + (wc * 64 + n * 16 + fr) * 32 + fg * 8);
#pragma unroll
    for (int m = 0; m < 4; ++m)
#pragma unroll
      for (int n = 0; n < 4; ++n)
        acc[m][n] = __builtin_amdgcn_mfma_f32_16x16x32_bf16(af[m], bb[n], acc[m][n], 0, 0, 0);
    __syncthreads();
  }
}

// K1: x (f32) -> xb (bf16), sq[i] = sum x[i]^2. One wave per row.
__global__ __launch_bounds__(256) void k_prep_x(const float* __restrict__ x,
                                                short* __restrict__ xb,
                                                float* __restrict__ sq) {
  const int row  = blockIdx.x * 4 + (threadIdx.x >> 6);
  const int lane = threadIdx.x & 63;
  const float* px = x + (size_t)row * DIM + lane * 8;
  const float4 v0 = *(const float4*)px;
  const float4 v1 = *(const float4*)(px + 4);
  float s = v0.x*v0.x + v0.y*v0.y + v0.z*v0.z + v0.w*v0.w +
            v1.x*v1.x + v1.y*v1.y + v1.z*v1.z + v1.w*v1.w;
  short8 o;
  o[0]=f2bf(v0.x); o[1]=f2bf(v0.y); o[2]=f2bf(v0.z); o[3]=f2bf(v0.w);
  o[4]=f2bf(v1.x); o[5]=f2bf(v1.y); o[6]=f2bf(v1.z); o[7]=f2bf(v1.w);
  *(short8*)(xb + (size_t)row * DIM + lane * 8) = o;
#pragma unroll
  for (int m = 32; m >= 1; m >>= 1) s += __shfl_xor(s, m);
  if (lane == 0) sq[row] = s;
}

// K1b: W (f32) -> Wb (bf16)
__global__ __launch_bounds__(256) void k_prep_w(const float* __restrict__ W,
                                                short* __restrict__ Wb) {
  const int idx = blockIdx.x * 256 + threadIdx.x;
  const float4 v0 = *(const float4*)(W + (size_t)idx * 8);
  const float4 v1 = *(const float4*)(W + (size_t)idx * 8 + 4);
  short8 o;
  o[0]=f2bf(v0.x); o[1]=f2bf(v0.y); o[2]=f2bf(v0.z); o[3]=f2bf(v0.w);
  o[4]=f2bf(v1.x); o[5]=f2bf(v1.y); o[6]=f2bf(v1.z); o[7]=f2bf(v1.w);
  *(short8*)(Wb + (size_t)idx * 8) = o;
}

// K2: YbT[o][i] = bf16( sum_d Wb[o][d] * xb[i][d] )  (Y = x@W.T, transposed)
__global__ __launch_bounds__(256) void k_ybt(const short* __restrict__ xb,
                                             const short* __restrict__ Wb,
                                             short* __restrict__ YbT) {
  __shared__ short smem[8192];
  f32x4 acc[4][4];
  ZERO_ACC4(acc);
  const int rowBase = blockIdx.y * 128;  // o
  const int colBase = blockIdx.x * 128;  // i
  gemm_core_nt(Wb + (size_t)rowBase * DIM, xb + (size_t)colBase * DIM,
               DIM, DIM, DIM, smem, acc);
  const int lane = threadIdx.x & 63, wid = threadIdx.x >> 6;
  const int wr = wid >> 1, wc = wid & 1, fr = lane & 15, fg = lane >> 4;
#pragma unroll
  for (int m = 0; m < 4; ++m)
#pragma unroll
    for (int n = 0; n < 4; ++n)
#pragma unroll
      for (int r = 0; r < 4; ++r) {
        const int ro = rowBase + wr * 64 + m * 16 + fg * 4 + r;
        const int ci = colBase + wc * 64 + n * 16 + fr;
        YbT[(size_t)ro * NPTS + ci] = f2bf(acc[m][n][r]);
      }
}

// K3: P[i][j] = bf16(exp(min(2*dot - si - sj,0)/2048)), rowsum +=.
// Symmetric: P[i][j]==P[j][i] exactly -> triangle grid (2080 tiles of 4096)
// when SW==8192; each off-diag tile is mirrored via LDS transpose, and its
// column-sums feed rowsum[j]. LDS P-tile repack (stride 136 shorts, swizzled)
// gives coalesced short8 stores for both orientations.
__global__ __launch_bounds__(256) void k_pmat(const short* __restrict__ xb,
                                              const float* __restrict__ sq,
                                              short* __restrict__ P,
                                              float* __restrict__ rowsum,
                                              int jbase, int SW) {
  __shared__ short lds[17408];   // max(16384 gemm, 128*136 repack) = 34 KiB
  f32x4 acc[4][4];
  ZERO_ACC4(acc);
  int bi, bj; bool mirror;
  if (gridDim.y > 1) {           // rectangular fallback (SW < 8192)
    bi = blockIdx.y; bj = blockIdx.x; mirror = false;
  } else {                       // upper-triangle enumeration
    int n = blockIdx.x; bi = 0;
    while (n >= 64 - bi) { n -= 64 - bi; ++bi; }
    bj = bi + n; mirror = (bj != bi);
  }
  const int rowBase = bi * 128;
  const int colOff  = bj * 128;          // column offset within P strip
  const int jglob   = jbase + colOff;
  gemm128(xb + (size_t)rowBase * DIM, xb + (size_t)jglob * DIM,
          DIM, DIM, DIM, lds, acc);

  const int tid = threadIdx.x, lane = tid & 63, wid = tid >> 6;
  const int wr = wid >> 1, wc = wid & 1, fr = lane & 15, fg = (lane >> 4) & 3;
  float sjv[4];
#pragma unroll
  for (int n = 0; n < 4; ++n) sjv[n] = sq[jglob + wc * 64 + n * 16 + fr];
  float cs[4] = {0.f, 0.f, 0.f, 0.f};
  // pass 1: exp, row-sum atomics, col partials, bf16 -> LDS (swizzled)
#pragma unroll
  for (int m = 0; m < 4; ++m) {
#pragma unroll
    for (int r = 0; r < 4; ++r) {
      const int il = wr * 64 + m * 16 + fg * 4 + r;
      const int i  = rowBase + il;
      const float si = sq[i];
      float rs = 0.f;
#pragma unroll
      for (int n = 0; n < 4; ++n) {
        const float t = fminf(2.f * acc[m][n][r] - si - sjv[n], 0.f) * (1.0f / 2048.0f);
        const float w = __expf(t);
        rs += w; cs[n] += w;
        const int jl = wc * 64 + n * 16 + fr;
        lds[il * 136 + (((jl >> 3) ^ (il & 7)) << 3) + (jl & 7)] = f2bf(w);
      }
      rs += __shfl_xor(rs, 1);
      rs += __shfl_xor(rs, 2);
      rs += __shfl_xor(rs, 4);
      rs += __shfl_xor(rs, 8);
      if (fr == 0) atomicAdd(&rowsum[i], rs);
    }
  }
  if (mirror) {
#pragma unroll
    for (int n = 0; n < 4; ++n) {
      cs[n] += __shfl_xor(cs[n], 16);
      cs[n] += __shfl_xor(cs[n], 32);
    }
    if (lane < 16) {
#pragma unroll
      for (int n = 0; n < 4; ++n)
        atomicAdd(&rowsum[jglob + wc * 64 + n * 16 + lane], cs[n]);
    }
  }
  __syncthreads();
  // pass 2: coalesced short8 stores of the tile
#pragma unroll
  for (int v = 0; v < 8; ++v) {
    const int g = v * 256 + tid;           // 2048 chunks: 128 rows x 16
    const int rl = g >> 4, c = g & 15;
    short8 val = *(const short8*)(lds + rl * 136 + ((c ^ (rl & 7)) << 3));
    *(short8*)(P + (size_t)(rowBase + rl) * SW + colOff + c * 8) = val;
  }
  // pass 2T: mirrored tile (rows j, cols i), coalesced stores
  if (mirror) {
#pragma unroll
    for (int v = 0; v < 8; ++v) {
      const int g = v * 256 + tid;
      const int jl = g >> 4, ci = g & 15;
      short8 o;
#pragma unroll
      for (int e = 0; e < 8; ++e)
        o[e] = lds[(ci * 8 + e) * 136 + ((((jl >> 3) ^ e)) << 3) + (jl & 7)];
      *(short8*)(P + (size_t)(jglob + jl) * SW + rowBase + ci * 8) = o;
    }
  }
}

// K4: out_acc[i][o] += sum_j P[i][j] * YbT[o][j]  (128^2 core, z = K-split)
__global__ __launch_bounds__(256) void k_pv(const short* __restrict__ P,
                                            const short* __restrict__ YbT,
                                            float* __restrict__ out_acc,
                                            int jbase, int SW, int klen) {
  __shared__ short lds[16384];   // 32 KiB single-buffer
  f32x4 acc[4][4];
  ZERO_ACC4(acc);
  const int rowBase = blockIdx.y * 128;  // i
  const int colBase = blockIdx.x * 128;  // o
  const int kz = blockIdx.z * klen;
  gemm128(P + (size_t)rowBase * SW + kz,
          YbT + (size_t)colBase * NPTS + jbase + kz,
          klen, SW, NPTS, lds, acc);
  const int lane = threadIdx.x & 63, wid = threadIdx.x >> 6;
  const int wr = wid >> 1, wc = wid & 1, fr = lane & 15, fg = (lane >> 4) & 3;
#pragma unroll
  for (int m = 0; m < 4; ++m)
#pragma unroll
    for (int n = 0; n < 4; ++n)
#pragma unroll
      for (int r = 0; r < 4; ++r) {
        const int i = rowBase + wr * 64 + m * 16 + fg * 4 + r;
        const int o = colBase + wc * 64 + n * 16 + fr;
        atomicAdd(&out_acc[(size_t)i * ODIM + o], acc[m][n][r]);
      }
}

// K5: out = out_acc / (rowsum + eps) + b
__global__ __launch_bounds__(256) void k_final(const float* __restrict__ out_acc,
                                               const float* __restrict__ rowsum,
                                               const float* __restrict__ bvec,
                                               float* __restrict__ out) {
  const int idx = blockIdx.x * 256 + threadIdx.x;
  const int i = idx >> 7;
  const int o = (idx & 127) << 2;
  const float inv = 1.f / (rowsum[i] + 1e-8f);
  const float4 a = *(const float4*)(out_acc + (size_t)i * ODIM + o);
  const float4 bb = *(const float4*)(bvec + o);
  float4 r;
  r.x = a.x * inv + bb.x;
  r.y = a.y * inv + bb.y;
  r.z = a.z * inv + bb.z;
  r.w = a.w * inv + bb.w;
  *(float4*)(out + (size_t)i * ODIM + o) = r;
}

extern "C" void kernel_launch(void* const* d_in, const int* in_sizes, int n_in,
                              void* d_out, int out_size, void* d_ws, size_t ws_size,
                              hipStream_t stream) {
  (void)in_sizes; (void)n_in; (void)out_size;
  const float* x = (const float*)d_in[0];
  const float* W = (const float*)d_in[1];
  const float* bvec = (const float*)d_in[2];
  float* out = (float*)d_out;
  char* ws = (char*)d_ws;

  // workspace carving (bytes)
  short* xb      = (short*)(ws + 0);                  //  8 MiB
  short* Wb      = (short*)(ws + 8388608);            //  0.5 MiB
  short* YbT     = (short*)(ws + 8912896);            //  8 MiB
  float* sq      = (float*)(ws + 17301504);           //  32 KiB
  float* rowsum  = (float*)(ws + 17334272);           //  32 KiB
  float* out_acc = (float*)(ws + 17367040);           //  16 MiB
  short* P       = (short*)(ws + 34144256);           //  up to 128 MiB

  // adaptive P-strip width so everything fits in ws (multiples of 128)
  size_t pav = ws_size > 34144256 ? ws_size - 34144256 : 0;
  int SW = 8192;
  while (SW > 128 && (size_t)NPTS * SW * 2 > pav) SW >>= 1;
  const int nstrips = NPTS / SW;
  int ksplit = SW / 2048;
  if (ksplit < 1) ksplit = 1;
  if (ksplit > 4) ksplit = 4;
  const int klen = SW / ksplit;

  hipMemsetAsync(rowsum, 0, NPTS * sizeof(float), stream);
  hipMemsetAsync(out_acc, 0, (size_t)NPTS * ODIM * sizeof(float), stream);

  k_prep_x<<<dim3(NPTS / 4), 256, 0, stream>>>(x, xb, sq);
  k_prep_w<<<dim3(ODIM * DIM / 8 / 256), 256, 0, stream>>>(W, Wb);
  k_ybt<<<dim3(NPTS / 128, ODIM / 128), 256, 0, stream>>>(xb, Wb, YbT);

  for (int s = 0; s < nstrips; ++s) {
    const int jbase = s * SW;
    if (SW == 8192) {
      // symmetric path: 64*65/2 = 2080 upper-triangle tiles, mirrored
      k_pmat<<<dim3(2080, 1), 256, 0, stream>>>(xb, sq, P, rowsum, 0, SW);
    } else {
      k_pmat<<<dim3(SW / 128, NPTS / 128), 256, 0, stream>>>(xb, sq, P, rowsum, jbase, SW);
    }
    k_pv<<<dim3(ODIM / 128, NPTS / 128, ksplit), 256, 0, stream>>>(P, YbT, out_acc, jbase, SW, klen);
  }

  k_final<<<dim3(NPTS * ODIM / 4 / 256), 256, 0, stream>>>(out_acc, rowsum, bvec, out);
}

// Round 9
// 337.704 us; speedup vs baseline: 1.0614x; 1.0614x over previous
//
#include <hip/hip_runtime.h>
#include <stdint.h>

#define NPTS 8192
#define DIM  512
#define ODIM 512

typedef __attribute__((ext_vector_type(8))) short short8;
typedef __attribute__((ext_vector_type(4))) float f32x4;

__device__ __forceinline__ void gload_lds16(const void* g, void* l) {
  __builtin_amdgcn_global_load_lds(
      (__attribute__((address_space(1))) void*)g,
      (__attribute__((address_space(3))) void*)l, 16, 0, 0);
}

// round-to-nearest-even f32 -> bf16 bits (values are finite here)
__device__ __forceinline__ short f2bf(float f) {
  uint32_t u = __float_as_uint(f);
  u = (u + 0x7FFFu + ((u >> 16) & 1u)) >> 16;
  return (short)u;
}

// counted-vmcnt barrier (T4)
#define VMB(N) do {                                          \
    asm volatile("s_waitcnt vmcnt(" #N ")" ::: "memory");    \
    __builtin_amdgcn_sched_barrier(0);                       \
    __builtin_amdgcn_s_barrier();                            \
    __builtin_amdgcn_sched_barrier(0);                       \
  } while (0)

// ---------------------------------------------------------------------------
// 256x256 NT GEMM core — round-4/7 schedule (best measured k_pmat core).
// ---------------------------------------------------------------------------
__device__ __forceinline__ void gemm256_8ph(const short* __restrict__ A,
                                            const short* __restrict__ B,
                                            int K, int lda, int ldb,
                                            short* lds, f32x4 acc[8][4]) {
  const int tid = threadIdx.x, wid = tid >> 6, lane = tid & 63;
  const int wr = wid >> 2, wc = wid & 3, fr = lane & 15, fg = (lane >> 4) & 3;
  const int nt = K >> 6;
  const int rp = tid >> 3, slot = tid & 7;
  const int ch = slot ^ (rp & 7);               // pre-swizzled source chunk

  const short* srcA[4]; const short* srcB[4];
#pragma unroll
  for (int u = 0; u < 4; ++u) {
    srcA[u] = A + (size_t)((u & 1) * 128 + (u >> 1) * 64 + rp) * lda + ch * 8;
    srcB[u] = B + (size_t)(((u * 2 + (rp >> 5)) & 3) * 64 + (u >> 1) * 32 + (rp & 31)) * ldb + ch * 8;
  }

  const int c0 = (fg ^ (fr & 7)) * 8;
  const int c1 = ((4 + fg) ^ (fr & 7)) * 8;
  const int aRow = wr * 64 + fr;                // + mh*128 + m*16
  const int bRow = wc * 32 + fr;                // + nh*128 + n*16

  // prologue: stage tile 0 in steady-state order SA0,SB0,SB1,SA1
#pragma unroll
  for (int s = 0; s < 2; ++s) gload_lds16(srcA[s], lds + s * 4096 + wid * 512);
#pragma unroll
  for (int s = 0; s < 2; ++s) gload_lds16(srcB[s], lds + 16384 + s * 4096 + wid * 512);
#pragma unroll
  for (int s = 2; s < 4; ++s) gload_lds16(srcB[s], lds + 16384 + s * 4096 + wid * 512);
#pragma unroll
  for (int s = 2; s < 4; ++s) gload_lds16(srcA[s], lds + s * 4096 + wid * 512);
  VMB(4);

  for (int t = 0; t < nt; ++t) {
    const int buf  = (t & 1) << 15;
    const int nbuf = buf ^ 32768;
    const bool pf  = (t + 1) < nt;
    const int k1   = (t + 1) << 6;
    const short* sA = lds + buf;
    const short* sB = lds + buf + 16384;
    short8 afA[4][2], afB[4][2], bb0[2][2], bb1[2][2];

    // ---- phase 0
#pragma unroll
    for (int m = 0; m < 4; ++m) {
      const int r = aRow + m * 16;
      afA[m][0] = *(const short8*)(sA + r * 64 + c0);
      afA[m][1] = *(const short8*)(sA + r * 64 + c1);
    }
#pragma unroll
    for (int n = 0; n < 2; ++n) {
      const int r = bRow + n * 16;
      bb0[n][0] = *(const short8*)(sB + r * 64 + c0);
      bb0[n][1] = *(const short8*)(sB + r * 64 + c1);
    }
    if (pf) {
#pragma unroll
      for (int s = 0; s < 2; ++s) gload_lds16(srcA[s] + k1, lds + nbuf + s * 4096 + wid * 512);
    }
    VMB(4);
    __builtin_amdgcn_s_setprio(1);
#pragma unroll
    for (int kk = 0; kk < 2; ++kk)
#pragma unroll
      for (int m = 0; m < 4; ++m)
#pragma unroll
        for (int n = 0; n < 2; ++n)
          acc[m][n] = __builtin_amdgcn_mfma_f32_16x16x32_bf16(afA[m][kk], bb0[n][kk], acc[m][n], 0, 0, 0);
    __builtin_amdgcn_s_setprio(0);

    // ---- phase 1
#pragma unroll
    for (int n = 0; n < 2; ++n) {
      const int r = 128 + bRow + n * 16;
      bb1[n][0] = *(const short8*)(sB + r * 64 + c0);
      bb1[n][1] = *(const short8*)(sB + r * 64 + c1);
    }
    if (pf) {
#pragma unroll
      for (int s = 0; s < 2; ++s) gload_lds16(srcB[s] + k1, lds + nbuf + 16384 + s * 4096 + wid * 512);
    }
    VMB(4);
    __builtin_amdgcn_s_setprio(1);
#pragma unroll
    for (int kk = 0; kk < 2; ++kk)
#pragma unroll
      for (int m = 0; m < 4; ++m)
#pragma unroll
        for (int n = 0; n < 2; ++n)
          acc[m][2 + n] = __builtin_amdgcn_mfma_f32_16x16x32_bf16(afA[m][kk], bb1[n][kk], acc[m][2 + n], 0, 0, 0);
    __builtin_amdgcn_s_setprio(0);

    // ---- phase 2
#pragma unroll
    for (int m = 0; m < 4; ++m) {
      const int r = 128 + aRow + m * 16;
      afB[m][0] = *(const short8*)(sA + r * 64 + c0);
      afB[m][1] = *(const short8*)(sA + r * 64 + c1);
    }
    if (pf) {
#pragma unroll
      for (int s = 2; s < 4; ++s) gload_lds16(srcB[s] + k1, lds + nbuf + 16384 + s * 4096 + wid * 512);
    }
    VMB(4);
    __builtin_amdgcn_s_setprio(1);
#pragma unroll
    for (int kk = 0; kk < 2; ++kk)
#pragma unroll
      for (int m = 0; m < 4; ++m)
#pragma unroll
        for (int n = 0; n < 2; ++n)
          acc[4 + m][2 + n] = __builtin_amdgcn_mfma_f32_16x16x32_bf16(afB[m][kk], bb1[n][kk], acc[4 + m][2 + n], 0, 0, 0);
    __builtin_amdgcn_s_setprio(0);

    // ---- phase 3
    if (pf) {
#pragma unroll
      for (int s = 2; s < 4; ++s) gload_lds16(srcA[s] + k1, lds + nbuf + s * 4096 + wid * 512);
    }
    VMB(4);
    __builtin_amdgcn_s_setprio(1);
#pragma unroll
    for (int kk = 0; kk < 2; ++kk)
#pragma unroll
      for (int m = 0; m < 4; ++m)
#pragma unroll
        for (int n = 0; n < 2; ++n)
          acc[4 + m][n] = __builtin_amdgcn_mfma_f32_16x16x32_bf16(afB[m][kk], bb0[n][kk], acc[4 + m][n], 0, 0, 0);
    __builtin_amdgcn_s_setprio(0);
  }
}

#define ZERO_ACC8(acc)                       \
  {                                          \
    f32x4 _z = {0.f, 0.f, 0.f, 0.f};         \
    _Pragma("unroll")                        \
    for (int m = 0; m < 8; ++m)              \
      _Pragma("unroll")                      \
      for (int n = 0; n < 4; ++n) acc[m][n] = _z; \
  }

// ---------------------------------------------------------------------------
// 128x128 NT core, BK=64, 4 waves, single-buffer 32 KiB (round-8 k_pv core).
// ---------------------------------------------------------------------------
__device__ __forceinline__ void gemm128(const short* __restrict__ A,
                                        const short* __restrict__ B,
                                        int K, int lda, int ldb,
                                        short* lds, f32x4 acc[4][4]) {
  const int tid = threadIdx.x, wid = tid >> 6, lane = tid & 63;
  const int wr = wid >> 1, wc = wid & 1, fr = lane & 15, fg = (lane >> 4) & 3;
  const int nt = K >> 6;
  const short* srcA[4]; const short* srcB[4]; int dst[4];
#pragma unroll
  for (int u = 0; u < 4; ++u) {
    const int g = u * 256 + tid;
    const int r = g >> 3;
    const int cl = (g & 7) ^ (r & 7);
    srcA[u] = A + (size_t)r * lda + cl * 8;
    srcB[u] = B + (size_t)r * ldb + cl * 8;
    dst[u] = (u * 256 + wid * 64) * 8;
  }
  short* sB = lds + 8192;
  const int c0 = (fg ^ (fr & 7)) * 8;
  const int c1 = ((4 + fg) ^ (fr & 7)) * 8;

  for (int t = 0; t < nt; ++t) {
    const int k0 = t << 6;
#pragma unroll
    for (int u = 0; u < 4; ++u) gload_lds16(srcA[u] + k0, lds + dst[u]);
#pragma unroll
    for (int u = 0; u < 4; ++u) gload_lds16(srcB[u] + k0, sB + dst[u]);
    __syncthreads();
    short8 af[4][2], bb[4][2];
#pragma unroll
    for (int m = 0; m < 4; ++m) {
      const int rr = (wr * 64 + m * 16 + fr) * 64;
      af[m][0] = *(const short8*)(lds + rr + c0);
      af[m][1] = *(const short8*)(lds + rr + c1);
    }
#pragma unroll
    for (int n = 0; n < 4; ++n) {
      const int rr = (wc * 64 + n * 16 + fr) * 64;
      bb[n][0] = *(const short8*)(sB + rr + c0);
      bb[n][1] = *(const short8*)(sB + rr + c1);
    }
#pragma unroll
    for (int kk = 0; kk < 2; ++kk)
#pragma unroll
      for (int m = 0; m < 4; ++m)
#pragma unroll
        for (int n = 0; n < 4; ++n)
          acc[m][n] = __builtin_amdgcn_mfma_f32_16x16x32_bf16(af[m][kk], bb[n][kk], acc[m][n], 0, 0, 0);
    __syncthreads();
  }
}

#define ZERO_ACC4(acc)                       \
  {                                          \
    f32x4 _z = {0.f, 0.f, 0.f, 0.f};         \
    _Pragma("unroll")                        \
    for (int m = 0; m < 4; ++m)              \
      _Pragma("unroll")                      \
      for (int n = 0; n < 4; ++n) acc[m][n] = _z; \
  }

// ---------------------------------------------------------------------------
// legacy 128x128 BK=32 core (small YbT GEMM only)
// ---------------------------------------------------------------------------
__device__ __forceinline__ void gemm_core_nt(const short* __restrict__ A,
                                             const short* __restrict__ B,
                                             int K, int lda, int ldb,
                                             short* smem, f32x4 acc[4][4]) {
  const int tid  = threadIdx.x;
  const int wid  = tid >> 6;
  const int lane = tid & 63;
  const int wr = wid >> 1, wc = wid & 1;
  const int sr = lane >> 2;
  const int sc = (lane & 3) << 3;
  const int fr = lane & 15, fg = lane >> 4;
  short* sA = smem;
  short* sB = smem + 4096;
  short* dA0 = sA + wid * 512;
  short* dA1 = sA + 2048 + wid * 512;
  short* dB0 = sB + wid * 512;
  short* dB1 = sB + 2048 + wid * 512;
  const short* pa0 = A + (size_t)(wid * 16 + sr) * lda + sc;
  const short* pa1 = A + (size_t)(64 + wid * 16 + sr) * lda + sc;
  const short* pb0 = B + (size_t)(wid * 16 + sr) * ldb + sc;
  const short* pb1 = B + (size_t)(64 + wid * 16 + sr) * ldb + sc;

  for (int k0 = 0; k0 < K; k0 += 32) {
    gload_lds16(pa0 + k0, dA0);
    gload_lds16(pa1 + k0, dA1);
    gload_lds16(pb0 + k0, dB0);
    gload_lds16(pb1 + k0, dB1);
    __syncthreads();
    short8 af[4], bb[4];
#pragma unroll
    for (int m = 0; m < 4; ++m)
      af[m] = *(const short8*)(sA + (wr * 64 + m * 16 + fr) * 32 + fg * 8);
#pragma unroll
    for (int n = 0; n < 4; ++n)
      bb[n] = *(const short8*)(sB + (wc * 64 + n * 16 + fr) * 32 + fg * 8);
#pragma unroll
    for (int m = 0; m < 4; ++m)
#pragma unroll
      for (int n = 0; n < 4; ++n)
        acc[m][n] = __builtin_amdgcn_mfma_f32_16x16x32_bf16(af[m], bb[n], acc[m][n], 0, 0, 0);
    __syncthreads();
  }
}

// K1: x (f32) -> xb (bf16), sq[i] = sum x[i]^2. One wave per row.
__global__ __launch_bounds__(256) void k_prep_x(const float* __restrict__ x,
                                                short* __restrict__ xb,
                                                float* __restrict__ sq) {
  const int row  = blockIdx.x * 4 + (threadIdx.x >> 6);
  const int lane = threadIdx.x & 63;
  const float* px = x + (size_t)row * DIM + lane * 8;
  const float4 v0 = *(const float4*)px;
  const float4 v1 = *(const float4*)(px + 4);
  float s = v0.x*v0.x + v0.y*v0.y + v0.z*v0.z + v0.w*v0.w +
            v1.x*v1.x + v1.y*v1.y + v1.z*v1.z + v1.w*v1.w;
  short8 o;
  o[0]=f2bf(v0.x); o[1]=f2bf(v0.y); o[2]=f2bf(v0.z); o[3]=f2bf(v0.w);
  o[4]=f2bf(v1.x); o[5]=f2bf(v1.y); o[6]=f2bf(v1.z); o[7]=f2bf(v1.w);
  *(short8*)(xb + (size_t)row * DIM + lane * 8) = o;
#pragma unroll
  for (int m = 32; m >= 1; m >>= 1) s += __shfl_xor(s, m);
  if (lane == 0) sq[row] = s;
}

// K1b: W (f32) -> Wb (bf16)
__global__ __launch_bounds__(256) void k_prep_w(const float* __restrict__ W,
                                                short* __restrict__ Wb) {
  const int idx = blockIdx.x * 256 + threadIdx.x;
  const float4 v0 = *(const float4*)(W + (size_t)idx * 8);
  const float4 v1 = *(const float4*)(W + (size_t)idx * 8 + 4);
  short8 o;
  o[0]=f2bf(v0.x); o[1]=f2bf(v0.y); o[2]=f2bf(v0.z); o[3]=f2bf(v0.w);
  o[4]=f2bf(v1.x); o[5]=f2bf(v1.y); o[6]=f2bf(v1.z); o[7]=f2bf(v1.w);
  *(short8*)(Wb + (size_t)idx * 8) = o;
}

// K2: YbT[o][i] = bf16( sum_d Wb[o][d] * xb[i][d] )
__global__ __launch_bounds__(256) void k_ybt(const short* __restrict__ xb,
                                             const short* __restrict__ Wb,
                                             short* __restrict__ YbT) {
  __shared__ short smem[8192];
  f32x4 acc[4][4];
  ZERO_ACC4(acc);
  const int rowBase = blockIdx.y * 128;  // o
  const int colBase = blockIdx.x * 128;  // i
  gemm_core_nt(Wb + (size_t)rowBase * DIM, xb + (size_t)colBase * DIM,
               DIM, DIM, DIM, smem, acc);
  const int lane = threadIdx.x & 63, wid = threadIdx.x >> 6;
  const int wr = wid >> 1, wc = wid & 1, fr = lane & 15, fg = lane >> 4;
#pragma unroll
  for (int m = 0; m < 4; ++m)
#pragma unroll
    for (int n = 0; n < 4; ++n)
#pragma unroll
      for (int r = 0; r < 4; ++r) {
        const int ro = rowBase + wr * 64 + m * 16 + fg * 4 + r;
        const int ci = colBase + wc * 64 + n * 16 + fr;
        YbT[(size_t)ro * NPTS + ci] = f2bf(acc[m][n][r]);
      }
}

// K3: symmetric triangular P with 256^2-8ph core + conflict-fixed mirror.
// LDS repack layout: cell (il,jl) at il*256 + (( (jl>>3) ^ ((il>>3)&7) ))*8
// + (jl&7). Row reads: 8-lane group spans 8 distinct chunk slots -> free.
// Transpose reads (il=ci*8+e): chunk = (jl>>3)^(ci&7) spans 8 slots -> 4-way.
__global__ __launch_bounds__(512, 2) void k_pmat(const short* __restrict__ xb,
                                                 const float* __restrict__ sq,
                                                 short* __restrict__ P,
                                                 float* __restrict__ rowsum,
                                                 int jbase, int SW) {
  __shared__ short lds[65536];   // 128 KiB: gemm staging, then 256x256 repack
  f32x4 acc[8][4];
  ZERO_ACC8(acc);
  int bi, bj; bool mirror;
  if (gridDim.y > 1) {           // rectangular fallback (SW < 8192)
    bi = blockIdx.y; bj = blockIdx.x; mirror = false;
  } else {                       // upper-triangle enumeration (32x32 tiles)
    int n = blockIdx.x; bi = 0;
    while (n >= 32 - bi) { n -= 32 - bi; ++bi; }
    bj = bi + n; mirror = (bj != bi);
  }
  const int rowBase = bi * 256;
  const int colOff  = bj * 256;
  const int jglob   = jbase + colOff;
  gemm256_8ph(xb + (size_t)rowBase * DIM, xb + (size_t)jglob * DIM,
              DIM, DIM, DIM, lds, acc);
  // After the core's last phase-3 barrier, all LDS reads are complete
  // block-wide -> safe to overwrite for repack.
  const int tid = threadIdx.x, lane = tid & 63, wid = tid >> 6;
  const int wr = wid >> 2, wc = wid & 3, fr = lane & 15, fg = (lane >> 4) & 3;
  float sjv[4];
#pragma unroll
  for (int n = 0; n < 4; ++n) sjv[n] = sq[jglob + wc * 64 + n * 16 + fr];
  float cs[4] = {0.f, 0.f, 0.f, 0.f};
  // pass 1: exp, rowsum atomics, col partials, paired bf16 -> LDS (4B writes)
#pragma unroll
  for (int m = 0; m < 8; ++m) {
#pragma unroll
    for (int r = 0; r < 4; ++r) {
      const int il = wr * 128 + m * 16 + fg * 4 + r;
      const int i  = rowBase + il;
      const float si = sq[i];
      float rs = 0.f;
#pragma unroll
      for (int n = 0; n < 4; ++n) {
        const int jl = wc * 64 + n * 16 + fr;
        const float t = fminf(2.f * acc[m][n][r] - si - sjv[n], 0.f) * (1.0f / 2048.0f);
        const float w = __expf(t);
        rs += w; cs[n] += w;
        const float wo = __shfl_xor(w, 1);   // partner col jl^1
        if ((fr & 1) == 0) {
          const uint32_t pair = (uint32_t)(uint16_t)f2bf(w) |
                                ((uint32_t)(uint16_t)f2bf(wo) << 16);
          const int pc = (jl >> 3) ^ ((il >> 3) & 7);
          *(uint32_t*)&lds[il * 256 + pc * 8 + (jl & 7)] = pair;
        }
      }
      rs += __shfl_xor(rs, 1);
      rs += __shfl_xor(rs, 2);
      rs += __shfl_xor(rs, 4);
      rs += __shfl_xor(rs, 8);
      if (fr == 0) atomicAdd(&rowsum[i], rs);
    }
  }
  if (mirror) {
#pragma unroll
    for (int n = 0; n < 4; ++n) {
      cs[n] += __shfl_xor(cs[n], 16);
      cs[n] += __shfl_xor(cs[n], 32);
    }
    if (lane < 16) {
#pragma unroll
      for (int n = 0; n < 4; ++n)
        atomicAdd(&rowsum[jglob + wc * 64 + n * 16 + lane], cs[n]);
    }
  }
  __syncthreads();
  // pass 2: direct tile, coalesced short8 stores (256 rows x 32 chunks)
#pragma unroll
  for (int v = 0; v < 16; ++v) {
    const int g = v * 512 + tid;
    const int rl = g >> 5, c = g & 31;
    const int pc = c ^ ((rl >> 3) & 7);
    short8 val = *(const short8*)(lds + rl * 256 + pc * 8);
    *(short8*)(P + (size_t)(rowBase + rl) * SW + colOff + c * 8) = val;
  }
  // pass 2T: mirrored tile, transpose-gather (4-way conflicts max)
  if (mirror) {
#pragma unroll
    for (int v = 0; v < 16; ++v) {
      const int g = v * 512 + tid;
      const int jl = g >> 5, ci = g & 31;
      short8 o;
#pragma unroll
      for (int e = 0; e < 8; ++e)
        o[e] = lds[(ci * 8 + e) * 256 + (((jl >> 3) ^ (ci & 7)) << 3) + (jl & 7)];
      *(short8*)(P + (size_t)(jglob + jl) * SW + rowBase + ci * 8) = o;
    }
  }
}

// K4: out_acc[i][o] += sum_j P[i][j]*YbT[o][j]. 128^2 core, z=K-split.
// XCD co-location: the 4 bx-tiles sharing a P strip-slice get dispatch ids
// == same mod 8 (distance 8) -> same XCD, co-resident -> P L2 reuse.
__global__ __launch_bounds__(256) void k_pv(const short* __restrict__ P,
                                            const short* __restrict__ YbT,
                                            float* __restrict__ out_acc,
                                            int jbase, int SW, int klen) {
  __shared__ short lds[16384];   // 32 KiB single-buffer
  f32x4 acc[4][4];
  ZERO_ACC4(acc);
  int bx = blockIdx.x, by = blockIdx.y, bz = blockIdx.z;
  if (gridDim.x == 4 && gridDim.y == 64 && gridDim.z == 4) {
    const int n = blockIdx.x + blockIdx.y * 4 + blockIdx.z * 256; // hw linear
    const int low3 = n & 7, rest = n >> 3;
    bx = rest & 3;
    const int q = ((rest >> 2) << 3) | low3;     // 0..255
    by = q >> 2; bz = q & 3;
  }
  const int rowBase = by * 128;  // i
  const int colBase = bx * 128;  // o
  const int kz = bz * klen;
  gemm128(P + (size_t)rowBase * SW + kz,
          YbT + (size_t)colBase * NPTS + jbase + kz,
          klen, SW, NPTS, lds, acc);
  const int lane = threadIdx.x & 63, wid = threadIdx.x >> 6;
  const int wr = wid >> 1, wc = wid & 1, fr = lane & 15, fg = (lane >> 4) & 3;
#pragma unroll
  for (int m = 0; m < 4; ++m)
#pragma unroll
    for (int n = 0; n < 4; ++n)
#pragma unroll
      for (int r = 0; r < 4; ++r) {
        const int i = rowBase + wr * 64 + m * 16 + fg * 4 + r;
        const int o = colBase + wc * 64 + n * 16 + fr;
        atomicAdd(&out_acc[(size_t)i * ODIM + o], acc[m][n][r]);
      }
}

// K5: out = out_acc / (rowsum + eps) + b
__global__ __launch_bounds__(256) void k_final(const float* __restrict__ out_acc,
                                               const float* __restrict__ rowsum,
                                               const float* __restrict__ bvec,
                                               float* __restrict__ out) {
  const int idx = blockIdx.x * 256 + threadIdx.x;
  const int i = idx >> 7;
  const int o = (idx & 127) << 2;
  const float inv = 1.f / (rowsum[i] + 1e-8f);
  const float4 a = *(const float4*)(out_acc + (size_t)i * ODIM + o);
  const float4 bb = *(const float4*)(bvec + o);
  float4 r;
  r.x = a.x * inv + bb.x;
  r.y = a.y * inv + bb.y;
  r.z = a.z * inv + bb.z;
  r.w = a.w * inv + bb.w;
  *(float4*)(out + (size_t)i * ODIM + o) = r;
}

extern "C" void kernel_launch(void* const* d_in, const int* in_sizes, int n_in,
                              void* d_out, int out_size, void* d_ws, size_t ws_size,
                              hipStream_t stream) {
  (void)in_sizes; (void)n_in; (void)out_size;
  const float* x = (const float*)d_in[0];
  const float* W = (const float*)d_in[1];
  const float* bvec = (const float*)d_in[2];
  float* out = (float*)d_out;
  char* ws = (char*)d_ws;

  // workspace carving (bytes)
  short* xb      = (short*)(ws + 0);                  //  8 MiB
  short* Wb      = (short*)(ws + 8388608);            //  0.5 MiB
  short* YbT     = (short*)(ws + 8912896);            //  8 MiB
  float* sq      = (float*)(ws + 17301504);           //  32 KiB
  float* rowsum  = (float*)(ws + 17334272);           //  32 KiB
  float* out_acc = (float*)(ws + 17367040);           //  16 MiB
  short* P       = (short*)(ws + 34144256);           //  up to 128 MiB

  // adaptive P-strip width so everything fits in ws (multiples of 256)
  size_t pav = ws_size > 34144256 ? ws_size - 34144256 : 0;
  int SW = 8192;
  while (SW > 256 && (size_t)NPTS * SW * 2 > pav) SW >>= 1;
  const int nstrips = NPTS / SW;
  int ksplit = SW / 2048;
  if (ksplit < 1) ksplit = 1;
  if (ksplit > 4) ksplit = 4;
  const int klen = SW / ksplit;

  hipMemsetAsync(rowsum, 0, NPTS * sizeof(float), stream);
  hipMemsetAsync(out_acc, 0, (size_t)NPTS * ODIM * sizeof(float), stream);

  k_prep_x<<<dim3(NPTS / 4), 256, 0, stream>>>(x, xb, sq);
  k_prep_w<<<dim3(ODIM * DIM / 8 / 256), 256, 0, stream>>>(W, Wb);
  k_ybt<<<dim3(NPTS / 128, ODIM / 128), 256, 0, stream>>>(xb, Wb, YbT);

  for (int s = 0; s < nstrips; ++s) {
    const int jbase = s * SW;
    if (SW == 8192) {
      // symmetric path: 32*33/2 = 528 upper-triangle 256^2 tiles, mirrored
      k_pmat<<<dim3(528, 1), 512, 0, stream>>>(xb, sq, P, rowsum, 0, SW);
    } else {
      k_pmat<<<dim3(SW / 256, NPTS / 256), 512, 0, stream>>>(xb, sq, P, rowsum, jbase, SW);
    }
    k_pv<<<dim3(ODIM / 128, NPTS / 128, ksplit), 256, 0, stream>>>(P, YbT, out_acc, jbase, SW, klen);
  }

  k_final<<<dim3(NPTS * ODIM / 4 / 256), 256, 0, stream>>>(out_acc, rowsum, bvec, out);
}